// Round 9
// baseline (458.511 us; speedup 1.0000x reference)
//
#include <hip/hip_runtime.h>
#include <math.h>

#define FIN 256
#define HF  256   // H*FO
#define NH  8

typedef __bf16 bf16x8 __attribute__((ext_vector_type(8)));
typedef float  f32x4  __attribute__((ext_vector_type(4)));

__device__ __forceinline__ unsigned short f2bf(float f) {
    unsigned u = __float_as_uint(f);
    unsigned r = (u + 0x7fffu + ((u >> 16) & 1u)) >> 16;
    return (unsigned short)r;
}
__device__ __forceinline__ float bf2f(unsigned short h) {
    return __uint_as_float(((unsigned)h) << 16);
}

// ---------------- convert (f32 -> bf16 hi|lo) + fused degree histogram ----------------
__global__ __launch_bounds__(256) void convert_hist_k(
    const float* __restrict__ x, const float* __restrict__ Wp,
    const float* __restrict__ Wskip, unsigned short* __restrict__ A2,
    unsigned short* __restrict__ W2, const int* __restrict__ ei,
    int* __restrict__ deg, int M, int E, int convBlocks)
{
    if ((int)blockIdx.x >= convBlocks) {
        const int b = blockIdx.x - convBlocks;
        int gid = b * 256 + threadIdx.x;
        int stride = 1024 * 256;
        for (int e = gid; e < E; e += stride)
            atomicAdd(&deg[ei[(size_t)E + e]], 1);
        return;
    }
    const int l = threadIdx.x & 63;
    const int row = blockIdx.x * 4 + (threadIdx.x >> 6);
    const int total = M + 512;
    if (row >= total) return;
    const float* src;
    unsigned short* dst;
    if (row < M) { src = x + (size_t)row * 256; dst = A2 + (size_t)row * 512; }
    else {
        int j = row - M;
        src = (j < 256) ? Wp + (size_t)j * 256 : Wskip + (size_t)(j - 256) * 256;
        dst = W2 + (size_t)j * 512;
    }
    float4 v = *(const float4*)&src[l * 4];
    ushort4 h, lo;
    h.x = f2bf(v.x); lo.x = f2bf(v.x - bf2f(h.x));
    h.y = f2bf(v.y); lo.y = f2bf(v.y - bf2f(h.y));
    h.z = f2bf(v.z); lo.z = f2bf(v.z - bf2f(h.z));
    h.w = f2bf(v.w); lo.w = f2bf(v.w - bf2f(h.w));
    *(ushort4*)&dst[l * 4]       = h;
    *(ushort4*)&dst[256 + l * 4] = lo;
}

// ---------------- MFMA GEMM: BK=32, 32KB LDS -> 4 blocks/CU ----------------
// cols 0-255: write projb (bf16) + fused scores (f32, exact from acc)
// cols 256-511: write out (f32) + bias
__device__ __forceinline__ void gload16(const void* g, void* l) {
    __builtin_amdgcn_global_load_lds(
        (const __attribute__((address_space(1))) void*)g,
        (__attribute__((address_space(3))) void*)l, 16, 0, 0);
}

__global__ __launch_bounds__(256) void mfma_gemm(
    const unsigned short* __restrict__ A2, const unsigned short* __restrict__ W2,
    const float* __restrict__ bias, const float* __restrict__ a_src,
    const float* __restrict__ a_trg, unsigned short* __restrict__ projb,
    float* __restrict__ ssrc, float* __restrict__ strg,
    float* __restrict__ out, int M)
{
    // 128 rows x 32 ushorts (64B) each = 8KB per array, 32KB total
    __shared__ __align__(16) unsigned short sAh[4096], sAl[4096], sBh[4096], sBl[4096];

    const int tid = threadIdx.x;
    const int l   = tid & 63;
    const int w   = tid >> 6;       // wave 0..3
    const int wr  = w >> 1, wc = w & 1;
    const int brow = blockIdx.x * 128;
    const int bcol = blockIdx.y * 128;

    f32x4 acc[4][4];
    #pragma unroll
    for (int a = 0; a < 4; ++a)
        #pragma unroll
        for (int b = 0; b < 4; ++b) acc[a][b] = (f32x4){0.f, 0.f, 0.f, 0.f};

    const int srow = l >> 2;               // 0..15 row within 16-row staging group
    const int sseg = (l & 3) ^ (srow & 3); // inverse-swizzled 16B segment (of 4/row)

    for (int kk = 0; kk < 8; ++kk) {
        #pragma unroll
        for (int i = 0; i < 2; ++i) {
            const int rl0 = w * 32 + i * 16;        // 16-row group start
            const int lds = rl0 * 32;               // ushort index of group base
            int ga = brow + rl0 + srow; if (ga >= M) ga = M - 1;
            const int gb = bcol + rl0 + srow;
            const unsigned short* gA = A2 + (size_t)ga * 512 + kk * 32 + sseg * 8;
            const unsigned short* gB = W2 + (size_t)gb * 512 + kk * 32 + sseg * 8;
            gload16(gA,       &sAh[lds]);
            gload16(gA + 256, &sAl[lds]);
            gload16(gB,       &sBh[lds]);
            gload16(gB + 256, &sBl[lds]);
        }
        __syncthreads();

        const int sg = (l >> 4) ^ (l & 3);          // swizzled read segment
        bf16x8 ah[4], al[4], bh[4], bl[4];
        #pragma unroll
        for (int f = 0; f < 4; ++f) {
            const int ra = wr * 64 + f * 16 + (l & 15);
            const int rb = wc * 64 + f * 16 + (l & 15);
            ah[f] = *(const bf16x8*)&sAh[ra * 32 + sg * 8];
            al[f] = *(const bf16x8*)&sAl[ra * 32 + sg * 8];
            bh[f] = *(const bf16x8*)&sBh[rb * 32 + sg * 8];
            bl[f] = *(const bf16x8*)&sBl[rb * 32 + sg * 8];
        }
        #pragma unroll
        for (int fm = 0; fm < 4; ++fm)
            #pragma unroll
            for (int fn = 0; fn < 4; ++fn) {
                acc[fm][fn] = __builtin_amdgcn_mfma_f32_16x16x32_bf16(ah[fm], bh[fn], acc[fm][fn], 0, 0, 0);
                acc[fm][fn] = __builtin_amdgcn_mfma_f32_16x16x32_bf16(ah[fm], bl[fn], acc[fm][fn], 0, 0, 0);
                acc[fm][fn] = __builtin_amdgcn_mfma_f32_16x16x32_bf16(al[fm], bh[fn], acc[fm][fn], 0, 0, 0);
            }
        __syncthreads();
    }

    // epilogue: C/D layout col=lane&15, row=(lane>>4)*4+q
    if (bcol < 256) {
        float as[4], at[4];
        #pragma unroll
        for (int fn = 0; fn < 4; ++fn) {
            const int col = bcol + wc * 64 + fn * 16 + (l & 15);
            as[fn] = a_src[col];
            at[fn] = a_trg[col];
        }
        #pragma unroll
        for (int fn = 0; fn < 4; ++fn) {
            const int col = bcol + wc * 64 + fn * 16 + (l & 15);
            #pragma unroll
            for (int fm = 0; fm < 4; ++fm) {
                const int r0 = brow + wr * 64 + fm * 16 + (l >> 4) * 4;
                #pragma unroll
                for (int q = 0; q < 4; ++q) {
                    const int row = r0 + q;
                    if (row < M) projb[(size_t)row * 256 + col] = f2bf(acc[fm][fn][q]);
                }
            }
        }
        const int headA = ((bcol + wc * 64) >> 5);
        const int headB = headA + 1;
        #pragma unroll
        for (int fm = 0; fm < 4; ++fm) {
            #pragma unroll
            for (int q = 0; q < 4; ++q) {
                float p0 = acc[fm][0][q] * as[0] + acc[fm][1][q] * as[1];
                float p1 = acc[fm][2][q] * as[2] + acc[fm][3][q] * as[3];
                float t0 = acc[fm][0][q] * at[0] + acc[fm][1][q] * at[1];
                float t1 = acc[fm][2][q] * at[2] + acc[fm][3][q] * at[3];
                #pragma unroll
                for (int m = 1; m < 16; m <<= 1) {
                    p0 += __shfl_xor(p0, m, 64);
                    p1 += __shfl_xor(p1, m, 64);
                    t0 += __shfl_xor(t0, m, 64);
                    t1 += __shfl_xor(t1, m, 64);
                }
                if ((l & 15) == 0) {
                    const int row = brow + wr * 64 + fm * 16 + (l >> 4) * 4 + q;
                    if (row < M) {
                        ssrc[(size_t)row * NH + headA] = p0;
                        ssrc[(size_t)row * NH + headB] = p1;
                        strg[(size_t)row * NH + headA] = t0;
                        strg[(size_t)row * NH + headB] = t1;
                    }
                }
            }
        }
    } else {
        #pragma unroll
        for (int fn = 0; fn < 4; ++fn) {
            const int col = bcol + wc * 64 + fn * 16 + (l & 15);
            const float bv = bias[col - 256];
            float* dst = out + (col - 256);
            #pragma unroll
            for (int fm = 0; fm < 4; ++fm) {
                const int r0 = brow + wr * 64 + fm * 16 + (l >> 4) * 4;
                #pragma unroll
                for (int q = 0; q < 4; ++q) {
                    const int row = r0 + q;
                    if (row < M) dst[(size_t)row * 256] = acc[fm][fn][q] + bv;
                }
            }
        }
    }
}

__device__ __forceinline__ float lrelu(float v) { return v > 0.f ? v : 0.2f * v; }

// ---------------- fused exclusive prefix scan of deg -> rp, cursor (1 block) --------
__global__ __launch_bounds__(1024) void scan_k(
    const int* __restrict__ deg, int* __restrict__ rp,
    int* __restrict__ cursor, int N, int E)
{
    __shared__ int sh[1024];
    const int t = threadIdx.x;
    const int C = (N + 1023) >> 10;
    const int b0 = t * C;
    const int b1 = min(b0 + C, N);
    int s = 0;
    for (int i = b0; i < b1; ++i) s += deg[i];
    sh[t] = s;
    __syncthreads();
    #pragma unroll
    for (int off = 1; off < 1024; off <<= 1) {
        int v = (t >= off) ? sh[t - off] : 0;
        __syncthreads();
        sh[t] += v;
        __syncthreads();
    }
    int excl = sh[t] - s;
    for (int i = b0; i < b1; ++i) {
        rp[i] = excl; cursor[i] = excl;
        excl += deg[i];
    }
    if (t == 0) rp[N] = E;
}

// ---------------- scatter: bucket src ids by target ----------------
__global__ __launch_bounds__(256) void scatter_k(
    const int* __restrict__ ei, int* __restrict__ cursor,
    int* __restrict__ col, int E)
{
    int gid = blockIdx.x * 256 + threadIdx.x;
    int stride = gridDim.x * 256;
    for (int e = gid; e < E; e += stride) {
        int s = ei[e];
        int t = ei[(size_t)E + e];
        int pos = atomicAdd(&cursor[t], 1);
        col[pos] = s;
    }
}

// ---------------- gather + finalize: one wave per node, 4 edges in flight ----------------
// Half-wave (32 lanes) owns 2 edges per iter: lane covers 8 bf16 cols (16B), head = hl>>2.
__global__ __launch_bounds__(256) void gather_k(
    const int* __restrict__ rp, const int* __restrict__ col,
    const float* __restrict__ ssrc, const float* __restrict__ strg,
    const unsigned short* __restrict__ projb, float* __restrict__ out, int N)
{
    const int lane = threadIdx.x & 63;
    const int node = blockIdx.x * 4 + (threadIdx.x >> 6);
    if (node >= N) return;
    const int half = lane >> 5;
    const int hl   = lane & 31;
    const int h    = hl >> 2;

    const float st = strg[(size_t)node * NH + h];
    const int beg = rp[node], end = rp[node + 1];

    float a0 = 0.f, a1 = 0.f, a2 = 0.f, a3 = 0.f,
          a4 = 0.f, a5 = 0.f, a6 = 0.f, a7 = 0.f, den = 0.f;

    for (int i0 = beg; i0 < end; i0 += 64) {
        int ci = (i0 + lane < end) ? col[i0 + lane] : 0;
        int cnt = end - i0; if (cnt > 64) cnt = 64;
        for (int k = 0; k < cnt; k += 4) {
            const int e0 = k + half * 2, e1 = e0 + 1;
            int s0 = __shfl(ci, e0 < 64 ? e0 : 63, 64);
            int s1 = __shfl(ci, e1 < 64 ? e1 : 63, 64);
            const bool v0 = e0 < cnt, v1 = e1 < cnt;
            uint4 r0 = *(const uint4*)&projb[(size_t)s0 * HF + hl * 8];
            uint4 r1 = *(const uint4*)&projb[(size_t)s1 * HF + hl * 8];
            float es0 = v0 ? __expf(lrelu(ssrc[(size_t)s0 * NH + h] + st)) : 0.f;
            float es1 = v1 ? __expf(lrelu(ssrc[(size_t)s1 * NH + h] + st)) : 0.f;
            a0 += __uint_as_float(r0.x << 16) * es0 + __uint_as_float(r1.x << 16) * es1;
            a1 += __uint_as_float(r0.x & 0xffff0000u) * es0 + __uint_as_float(r1.x & 0xffff0000u) * es1;
            a2 += __uint_as_float(r0.y << 16) * es0 + __uint_as_float(r1.y << 16) * es1;
            a3 += __uint_as_float(r0.y & 0xffff0000u) * es0 + __uint_as_float(r1.y & 0xffff0000u) * es1;
            a4 += __uint_as_float(r0.z << 16) * es0 + __uint_as_float(r1.z << 16) * es1;
            a5 += __uint_as_float(r0.z & 0xffff0000u) * es0 + __uint_as_float(r1.z & 0xffff0000u) * es1;
            a6 += __uint_as_float(r0.w << 16) * es0 + __uint_as_float(r1.w << 16) * es1;
            a7 += __uint_as_float(r0.w & 0xffff0000u) * es0 + __uint_as_float(r1.w & 0xffff0000u) * es1;
            den += es0 + es1;
        }
    }

    // combine the two halves (lane i and i+32 hold same col-range)
    a0 += __shfl_xor(a0, 32, 64);  a1 += __shfl_xor(a1, 32, 64);
    a2 += __shfl_xor(a2, 32, 64);  a3 += __shfl_xor(a3, 32, 64);
    a4 += __shfl_xor(a4, 32, 64);  a5 += __shfl_xor(a5, 32, 64);
    a6 += __shfl_xor(a6, 32, 64);  a7 += __shfl_xor(a7, 32, 64);
    den += __shfl_xor(den, 32, 64);

    const float inv = 1.f / (den + 1e-16f);
    const size_t ob = (size_t)node * HF + hl * 8 + half * 4;
    float4 sk = *(const float4*)&out[ob];
    float c0, c1, c2, c3;
    if (half == 0) { c0 = a0; c1 = a1; c2 = a2; c3 = a3; }
    else           { c0 = a4; c1 = a5; c2 = a6; c3 = a7; }
    float4 v;
    v.x = c0 * inv + sk.x;
    v.y = c1 * inv + sk.y;
    v.z = c2 * inv + sk.z;
    v.w = c3 * inv + sk.w;
    v.x = v.x > 0.f ? v.x : expm1f(v.x);
    v.y = v.y > 0.f ? v.y : expm1f(v.y);
    v.z = v.z > 0.f ? v.z : expm1f(v.z);
    v.w = v.w > 0.f ? v.w : expm1f(v.w);
    *(float4*)&out[ob] = v;
}

extern "C" void kernel_launch(void* const* d_in, const int* in_sizes, int n_in,
                              void* d_out, int out_size, void* d_ws, size_t ws_size,
                              hipStream_t stream) {
    const float* x     = (const float*)d_in[0];
    const int*   ei    = (const int*)d_in[1];
    const float* Wp    = (const float*)d_in[2];
    const float* a_src = (const float*)d_in[3];
    const float* a_trg = (const float*)d_in[4];
    const float* Wskip = (const float*)d_in[5];
    const float* bias  = (const float*)d_in[6];
    float* out = (float*)d_out;

    const int N = in_sizes[0] / FIN;
    const int E = in_sizes[1] / 2;

    // workspace layout
    unsigned short* projb = (unsigned short*)d_ws;               // N*HF bf16
    float* ssrc          = (float*)(projb + (size_t)N * HF);     // N*NH
    float* strg          = ssrc + (size_t)N * NH;                // N*NH
    unsigned short* A2   = (unsigned short*)(strg + (size_t)N * NH);  // N*512
    unsigned short* W2   = A2 + (size_t)N * 512;                 // 512*512
    int* deg             = (int*)(W2 + 512 * 512);               // N
    int* rp              = deg + N;                              // N+1
    int* cursor          = rp + (N + 1);                         // N
    int* col             = cursor + N;                           // E

    hipMemsetAsync(deg, 0, (size_t)N * sizeof(int), stream);

    const int convBlocks = (N + 512 + 3) / 4;
    convert_hist_k<<<convBlocks + 1024, 256, 0, stream>>>(
        x, Wp, Wskip, A2, W2, ei, deg, N, E, convBlocks);

    dim3 ggrid((N + 127) / 128, 4);
    mfma_gemm<<<ggrid, 256, 0, stream>>>(A2, W2, bias, a_src, a_trg,
                                         projb, ssrc, strg, out, N);

    scan_k<<<1, 1024, 0, stream>>>(deg, rp, cursor, N, E);

    scatter_k<<<1024, 256, 0, stream>>>(ei, cursor, col, E);

    gather_k<<<(N + 3) / 4, 256, 0, stream>>>(rp, col, ssrc, strg, projb, out, N);
}

// Round 11
// 366.324 us; speedup vs baseline: 1.2517x; 1.2517x over previous
//
#include <hip/hip_runtime.h>
#include <math.h>

#define FIN 256
#define HF  256   // H*FO
#define NH  8

typedef __bf16 bf16x8 __attribute__((ext_vector_type(8)));
typedef float  f32x4  __attribute__((ext_vector_type(4)));

__device__ __forceinline__ unsigned short f2bf(float f) {
    unsigned u = __float_as_uint(f);
    unsigned r = (u + 0x7fffu + ((u >> 16) & 1u)) >> 16;
    return (unsigned short)r;
}
__device__ __forceinline__ float bf2f(unsigned short h) {
    return __uint_as_float(((unsigned)h) << 16);
}

// ---------------- convert (f32 -> bf16 hi|lo) + fused degree histogram ----------------
__global__ __launch_bounds__(256) void convert_hist_k(
    const float* __restrict__ x, const float* __restrict__ Wp,
    const float* __restrict__ Wskip, unsigned short* __restrict__ A2,
    unsigned short* __restrict__ W2, const int* __restrict__ ei,
    int* __restrict__ deg, int M, int E, int convBlocks)
{
    if ((int)blockIdx.x >= convBlocks) {
        const int b = blockIdx.x - convBlocks;
        int gid = b * 256 + threadIdx.x;
        int stride = 1024 * 256;
        for (int e = gid; e < E; e += stride)
            atomicAdd(&deg[ei[(size_t)E + e]], 1);
        return;
    }
    const int l = threadIdx.x & 63;
    const int row = blockIdx.x * 4 + (threadIdx.x >> 6);
    const int total = M + 512;
    if (row >= total) return;
    const float* src;
    unsigned short* dst;
    if (row < M) { src = x + (size_t)row * 256; dst = A2 + (size_t)row * 512; }
    else {
        int j = row - M;
        src = (j < 256) ? Wp + (size_t)j * 256 : Wskip + (size_t)(j - 256) * 256;
        dst = W2 + (size_t)j * 512;
    }
    float4 v = *(const float4*)&src[l * 4];
    ushort4 h, lo;
    h.x = f2bf(v.x); lo.x = f2bf(v.x - bf2f(h.x));
    h.y = f2bf(v.y); lo.y = f2bf(v.y - bf2f(h.y));
    h.z = f2bf(v.z); lo.z = f2bf(v.z - bf2f(h.z));
    h.w = f2bf(v.w); lo.w = f2bf(v.w - bf2f(h.w));
    *(ushort4*)&dst[l * 4]       = h;
    *(ushort4*)&dst[256 + l * 4] = lo;
}

// ---------------- MFMA GEMM: BK=32, 32KB LDS -> 4 blocks/CU ----------------
// cols 0-255: write projb (bf16) + fused scores (f32, exact from acc)
// cols 256-511: write out (f32) + bias
__device__ __forceinline__ void gload16(const void* g, void* l) {
    __builtin_amdgcn_global_load_lds(
        (const __attribute__((address_space(1))) void*)g,
        (__attribute__((address_space(3))) void*)l, 16, 0, 0);
}

__global__ __launch_bounds__(256) void mfma_gemm(
    const unsigned short* __restrict__ A2, const unsigned short* __restrict__ W2,
    const float* __restrict__ bias, const float* __restrict__ a_src,
    const float* __restrict__ a_trg, unsigned short* __restrict__ projb,
    float* __restrict__ ssrc, float* __restrict__ strg,
    float* __restrict__ out, int M)
{
    // 128 rows x 32 ushorts (64B) each = 8KB per array, 32KB total
    __shared__ __align__(16) unsigned short sAh[4096], sAl[4096], sBh[4096], sBl[4096];

    const int tid = threadIdx.x;
    const int l   = tid & 63;
    const int w   = tid >> 6;       // wave 0..3
    const int wr  = w >> 1, wc = w & 1;
    const int brow = blockIdx.x * 128;
    const int bcol = blockIdx.y * 128;

    f32x4 acc[4][4];
    #pragma unroll
    for (int a = 0; a < 4; ++a)
        #pragma unroll
        for (int b = 0; b < 4; ++b) acc[a][b] = (f32x4){0.f, 0.f, 0.f, 0.f};

    const int srow = l >> 2;               // 0..15 row within 16-row staging group
    const int sseg = (l & 3) ^ (srow & 3); // inverse-swizzled 16B segment (of 4/row)

    for (int kk = 0; kk < 8; ++kk) {
        #pragma unroll
        for (int i = 0; i < 2; ++i) {
            const int rl0 = w * 32 + i * 16;        // 16-row group start
            const int lds = rl0 * 32;               // ushort index of group base
            int ga = brow + rl0 + srow; if (ga >= M) ga = M - 1;
            const int gb = bcol + rl0 + srow;
            const unsigned short* gA = A2 + (size_t)ga * 512 + kk * 32 + sseg * 8;
            const unsigned short* gB = W2 + (size_t)gb * 512 + kk * 32 + sseg * 8;
            gload16(gA,       &sAh[lds]);
            gload16(gA + 256, &sAl[lds]);
            gload16(gB,       &sBh[lds]);
            gload16(gB + 256, &sBl[lds]);
        }
        __syncthreads();

        const int sg = (l >> 4) ^ (l & 3);          // swizzled read segment
        bf16x8 ah[4], al[4], bh[4], bl[4];
        #pragma unroll
        for (int f = 0; f < 4; ++f) {
            const int ra = wr * 64 + f * 16 + (l & 15);
            const int rb = wc * 64 + f * 16 + (l & 15);
            ah[f] = *(const bf16x8*)&sAh[ra * 32 + sg * 8];
            al[f] = *(const bf16x8*)&sAl[ra * 32 + sg * 8];
            bh[f] = *(const bf16x8*)&sBh[rb * 32 + sg * 8];
            bl[f] = *(const bf16x8*)&sBl[rb * 32 + sg * 8];
        }
        #pragma unroll
        for (int fm = 0; fm < 4; ++fm)
            #pragma unroll
            for (int fn = 0; fn < 4; ++fn) {
                acc[fm][fn] = __builtin_amdgcn_mfma_f32_16x16x32_bf16(ah[fm], bh[fn], acc[fm][fn], 0, 0, 0);
                acc[fm][fn] = __builtin_amdgcn_mfma_f32_16x16x32_bf16(ah[fm], bl[fn], acc[fm][fn], 0, 0, 0);
                acc[fm][fn] = __builtin_amdgcn_mfma_f32_16x16x32_bf16(al[fm], bh[fn], acc[fm][fn], 0, 0, 0);
            }
        __syncthreads();
    }

    // epilogue: C/D layout col=lane&15, row=(lane>>4)*4+q
    if (bcol < 256) {
        float as[4], at[4];
        #pragma unroll
        for (int fn = 0; fn < 4; ++fn) {
            const int col = bcol + wc * 64 + fn * 16 + (l & 15);
            as[fn] = a_src[col];
            at[fn] = a_trg[col];
        }
        #pragma unroll
        for (int fn = 0; fn < 4; ++fn) {
            const int col = bcol + wc * 64 + fn * 16 + (l & 15);
            #pragma unroll
            for (int fm = 0; fm < 4; ++fm) {
                const int r0 = brow + wr * 64 + fm * 16 + (l >> 4) * 4;
                #pragma unroll
                for (int q = 0; q < 4; ++q) {
                    const int row = r0 + q;
                    if (row < M) projb[(size_t)row * 256 + col] = f2bf(acc[fm][fn][q]);
                }
            }
        }
        const int headA = ((bcol + wc * 64) >> 5);
        const int headB = headA + 1;
        #pragma unroll
        for (int fm = 0; fm < 4; ++fm) {
            #pragma unroll
            for (int q = 0; q < 4; ++q) {
                float p0 = acc[fm][0][q] * as[0] + acc[fm][1][q] * as[1];
                float p1 = acc[fm][2][q] * as[2] + acc[fm][3][q] * as[3];
                float t0 = acc[fm][0][q] * at[0] + acc[fm][1][q] * at[1];
                float t1 = acc[fm][2][q] * at[2] + acc[fm][3][q] * at[3];
                #pragma unroll
                for (int m = 1; m < 16; m <<= 1) {
                    p0 += __shfl_xor(p0, m, 64);
                    p1 += __shfl_xor(p1, m, 64);
                    t0 += __shfl_xor(t0, m, 64);
                    t1 += __shfl_xor(t1, m, 64);
                }
                if ((l & 15) == 0) {
                    const int row = brow + wr * 64 + fm * 16 + (l >> 4) * 4 + q;
                    if (row < M) {
                        ssrc[(size_t)row * NH + headA] = p0;
                        ssrc[(size_t)row * NH + headB] = p1;
                        strg[(size_t)row * NH + headA] = t0;
                        strg[(size_t)row * NH + headB] = t1;
                    }
                }
            }
        }
    } else {
        #pragma unroll
        for (int fn = 0; fn < 4; ++fn) {
            const int col = bcol + wc * 64 + fn * 16 + (l & 15);
            const float bv = bias[col - 256];
            float* dst = out + (col - 256);
            #pragma unroll
            for (int fm = 0; fm < 4; ++fm) {
                const int r0 = brow + wr * 64 + fm * 16 + (l >> 4) * 4;
                #pragma unroll
                for (int q = 0; q < 4; ++q) {
                    const int row = r0 + q;
                    if (row < M) dst[(size_t)row * 256] = acc[fm][fn][q] + bv;
                }
            }
        }
    }
}

__device__ __forceinline__ float lrelu(float v) { return v > 0.f ? v : 0.2f * v; }

// ---------------- exclusive prefix scan of deg -> rp (multi-block, proven) ----------------
__global__ __launch_bounds__(256) void scan1_k(
    const int* __restrict__ deg, int* __restrict__ rp, int* __restrict__ bsum, int N)
{
    __shared__ int sh[256];
    const int tid = threadIdx.x;
    const int base = blockIdx.x * 4096 + tid * 16;
    int v[16], pre[16];
    int s = 0;
    #pragma unroll
    for (int i = 0; i < 16; ++i) {
        int idx = base + i;
        v[i] = (idx < N) ? deg[idx] : 0;
        pre[i] = s; s += v[i];
    }
    sh[tid] = s;
    __syncthreads();
    #pragma unroll
    for (int off = 1; off < 256; off <<= 1) {
        int t = (tid >= off) ? sh[tid - off] : 0;
        __syncthreads();
        sh[tid] += t;
        __syncthreads();
    }
    int texcl = sh[tid] - s;
    #pragma unroll
    for (int i = 0; i < 16; ++i) {
        int idx = base + i;
        if (idx < N) rp[idx] = texcl + pre[i];
    }
    if (tid == 255) bsum[blockIdx.x] = sh[255];
}

__global__ void scan2_k(int* bsum, int nsb) {
    if (threadIdx.x == 0 && blockIdx.x == 0) {
        int s = 0;
        for (int b = 0; b < nsb; ++b) { int v = bsum[b]; bsum[b] = s; s += v; }
    }
}

__global__ __launch_bounds__(256) void scan3_k(
    int* __restrict__ rp, const int* __restrict__ bsum,
    int* __restrict__ cursor, int N, int E)
{
    int gid = blockIdx.x * 256 + threadIdx.x;
    if (gid < N) {
        int v = rp[gid] + bsum[gid >> 12];
        rp[gid] = v;
        cursor[gid] = v;
    }
    if (gid == 0) rp[N] = E;
}

// ---------------- scatter: bucket src ids by target ----------------
__global__ __launch_bounds__(256) void scatter_k(
    const int* __restrict__ ei, int* __restrict__ cursor,
    int* __restrict__ col, int E)
{
    int gid = blockIdx.x * 256 + threadIdx.x;
    int stride = gridDim.x * 256;
    for (int e = gid; e < E; e += stride) {
        int s = ei[e];
        int t = ei[(size_t)E + e];
        int pos = atomicAdd(&cursor[t], 1);
        col[pos] = s;
    }
}

// ---------------- gather + finalize: one wave per node, 4 edges in flight ----------------
__global__ __launch_bounds__(256) void gather_k(
    const int* __restrict__ rp, const int* __restrict__ col,
    const float* __restrict__ ssrc, const float* __restrict__ strg,
    const unsigned short* __restrict__ projb, float* __restrict__ out, int N)
{
    const int lane = threadIdx.x & 63;
    const int node = blockIdx.x * 4 + (threadIdx.x >> 6);
    if (node >= N) return;
    const int half = lane >> 5;
    const int hl   = lane & 31;
    const int h    = hl >> 2;

    const float st = strg[(size_t)node * NH + h];
    const int beg = rp[node], end = rp[node + 1];

    float a0 = 0.f, a1 = 0.f, a2 = 0.f, a3 = 0.f,
          a4 = 0.f, a5 = 0.f, a6 = 0.f, a7 = 0.f, den = 0.f;

    for (int i0 = beg; i0 < end; i0 += 64) {
        int ci = (i0 + lane < end) ? col[i0 + lane] : 0;
        int cnt = end - i0; if (cnt > 64) cnt = 64;
        for (int k = 0; k < cnt; k += 4) {
            const int e0 = k + half * 2, e1 = e0 + 1;
            int s0 = __shfl(ci, e0 < 64 ? e0 : 63, 64);
            int s1 = __shfl(ci, e1 < 64 ? e1 : 63, 64);
            const bool v0 = e0 < cnt, v1 = e1 < cnt;
            uint4 r0 = *(const uint4*)&projb[(size_t)s0 * HF + hl * 8];
            uint4 r1 = *(const uint4*)&projb[(size_t)s1 * HF + hl * 8];
            float es0 = v0 ? __expf(lrelu(ssrc[(size_t)s0 * NH + h] + st)) : 0.f;
            float es1 = v1 ? __expf(lrelu(ssrc[(size_t)s1 * NH + h] + st)) : 0.f;
            a0 += __uint_as_float(r0.x << 16) * es0 + __uint_as_float(r1.x << 16) * es1;
            a1 += __uint_as_float(r0.x & 0xffff0000u) * es0 + __uint_as_float(r1.x & 0xffff0000u) * es1;
            a2 += __uint_as_float(r0.y << 16) * es0 + __uint_as_float(r1.y << 16) * es1;
            a3 += __uint_as_float(r0.y & 0xffff0000u) * es0 + __uint_as_float(r1.y & 0xffff0000u) * es1;
            a4 += __uint_as_float(r0.z << 16) * es0 + __uint_as_float(r1.z << 16) * es1;
            a5 += __uint_as_float(r0.z & 0xffff0000u) * es0 + __uint_as_float(r1.z & 0xffff0000u) * es1;
            a6 += __uint_as_float(r0.w << 16) * es0 + __uint_as_float(r1.w << 16) * es1;
            a7 += __uint_as_float(r0.w & 0xffff0000u) * es0 + __uint_as_float(r1.w & 0xffff0000u) * es1;
            den += es0 + es1;
        }
    }

    // combine the two halves (lane i and i+32 hold same col-range)
    a0 += __shfl_xor(a0, 32, 64);  a1 += __shfl_xor(a1, 32, 64);
    a2 += __shfl_xor(a2, 32, 64);  a3 += __shfl_xor(a3, 32, 64);
    a4 += __shfl_xor(a4, 32, 64);  a5 += __shfl_xor(a5, 32, 64);
    a6 += __shfl_xor(a6, 32, 64);  a7 += __shfl_xor(a7, 32, 64);
    den += __shfl_xor(den, 32, 64);

    const float inv = 1.f / (den + 1e-16f);
    const size_t ob = (size_t)node * HF + hl * 8 + half * 4;
    float4 sk = *(const float4*)&out[ob];
    float c0, c1, c2, c3;
    if (half == 0) { c0 = a0; c1 = a1; c2 = a2; c3 = a3; }
    else           { c0 = a4; c1 = a5; c2 = a6; c3 = a7; }
    float4 v;
    v.x = c0 * inv + sk.x;
    v.y = c1 * inv + sk.y;
    v.z = c2 * inv + sk.z;
    v.w = c3 * inv + sk.w;
    v.x = v.x > 0.f ? v.x : expm1f(v.x);
    v.y = v.y > 0.f ? v.y : expm1f(v.y);
    v.z = v.z > 0.f ? v.z : expm1f(v.z);
    v.w = v.w > 0.f ? v.w : expm1f(v.w);
    *(float4*)&out[ob] = v;
}

extern "C" void kernel_launch(void* const* d_in, const int* in_sizes, int n_in,
                              void* d_out, int out_size, void* d_ws, size_t ws_size,
                              hipStream_t stream) {
    const float* x     = (const float*)d_in[0];
    const int*   ei    = (const int*)d_in[1];
    const float* Wp    = (const float*)d_in[2];
    const float* a_src = (const float*)d_in[3];
    const float* a_trg = (const float*)d_in[4];
    const float* Wskip = (const float*)d_in[5];
    const float* bias  = (const float*)d_in[6];
    float* out = (float*)d_out;

    const int N = in_sizes[0] / FIN;
    const int E = in_sizes[1] / 2;
    const int nsb = (N + 4095) / 4096;

    // workspace layout
    unsigned short* projb = (unsigned short*)d_ws;               // N*HF bf16
    float* ssrc          = (float*)(projb + (size_t)N * HF);     // N*NH
    float* strg          = ssrc + (size_t)N * NH;                // N*NH
    unsigned short* A2   = (unsigned short*)(strg + (size_t)N * NH);  // N*512
    unsigned short* W2   = A2 + (size_t)N * 512;                 // 512*512
    int* deg             = (int*)(W2 + 512 * 512);               // N
    int* rp              = deg + N;                              // N+1
    int* cursor          = rp + (N + 1);                         // N
    int* bsum            = cursor + N;                           // 16
    int* col             = bsum + 16;                            // E

    hipMemsetAsync(deg, 0, (size_t)N * sizeof(int), stream);

    const int convBlocks = (N + 512 + 3) / 4;
    convert_hist_k<<<convBlocks + 1024, 256, 0, stream>>>(
        x, Wp, Wskip, A2, W2, ei, deg, N, E, convBlocks);

    dim3 ggrid((N + 127) / 128, 4);
    mfma_gemm<<<ggrid, 256, 0, stream>>>(A2, W2, bias, a_src, a_trg,
                                         projb, ssrc, strg, out, N);

    scan1_k<<<nsb, 256, 0, stream>>>(deg, rp, bsum, N);
    scan2_k<<<1, 64, 0, stream>>>(bsum, nsb);
    scan3_k<<<(N + 255) / 256, 256, 0, stream>>>(rp, bsum, cursor, N, E);

    scatter_k<<<1024, 256, 0, stream>>>(ei, cursor, col, E);

    gather_k<<<(N + 3) / 4, 256, 0, stream>>>(rp, col, ssrc, strg, projb, out, N);
}

// Round 13
// 353.785 us; speedup vs baseline: 1.2960x; 1.0354x over previous
//
#include <hip/hip_runtime.h>
#include <math.h>

#define FIN 256
#define HF  256   // H*FO
#define NH  8

typedef __bf16 bf16x8 __attribute__((ext_vector_type(8)));
typedef float  f32x4  __attribute__((ext_vector_type(4)));

__device__ __forceinline__ unsigned short f2bf(float f) {
    unsigned u = __float_as_uint(f);
    unsigned r = (u + 0x7fffu + ((u >> 16) & 1u)) >> 16;
    return (unsigned short)r;
}
__device__ __forceinline__ float bf2f(unsigned short h) {
    return __uint_as_float(((unsigned)h) << 16);
}

// ---------------- convert (f32 -> bf16 hi|lo) + fused degree histogram ----------------
__global__ __launch_bounds__(256) void convert_hist_k(
    const float* __restrict__ x, const float* __restrict__ Wp,
    const float* __restrict__ Wskip, unsigned short* __restrict__ A2,
    unsigned short* __restrict__ W2, const int* __restrict__ ei,
    int* __restrict__ deg, int M, int E, int convBlocks)
{
    if ((int)blockIdx.x >= convBlocks) {
        const int b = blockIdx.x - convBlocks;
        int gid = b * 256 + threadIdx.x;
        int stride = 1024 * 256;
        for (int e = gid; e < E; e += stride)
            atomicAdd(&deg[ei[(size_t)E + e]], 1);
        return;
    }
    const int l = threadIdx.x & 63;
    const int row = blockIdx.x * 4 + (threadIdx.x >> 6);
    const int total = M + 512;
    if (row >= total) return;
    const float* src;
    unsigned short* dst;
    if (row < M) { src = x + (size_t)row * 256; dst = A2 + (size_t)row * 512; }
    else {
        int j = row - M;
        src = (j < 256) ? Wp + (size_t)j * 256 : Wskip + (size_t)(j - 256) * 256;
        dst = W2 + (size_t)j * 512;
    }
    float4 v = *(const float4*)&src[l * 4];
    ushort4 h, lo;
    h.x = f2bf(v.x); lo.x = f2bf(v.x - bf2f(h.x));
    h.y = f2bf(v.y); lo.y = f2bf(v.y - bf2f(h.y));
    h.z = f2bf(v.z); lo.z = f2bf(v.z - bf2f(h.z));
    h.w = f2bf(v.w); lo.w = f2bf(v.w - bf2f(h.w));
    *(ushort4*)&dst[l * 4]       = h;
    *(ushort4*)&dst[256 + l * 4] = lo;
}

// ---------------- MFMA GEMM (R6/R8-proven: BK=64, 64KB LDS, 0 conflicts) ----------------
// cols 0-255: write projb (bf16) + fused scores (f32, exact from acc)
// cols 256-511: write out (f32) + bias
__device__ __forceinline__ void gload16(const void* g, void* l) {
    __builtin_amdgcn_global_load_lds(
        (const __attribute__((address_space(1))) void*)g,
        (__attribute__((address_space(3))) void*)l, 16, 0, 0);
}

__global__ __launch_bounds__(256) void mfma_gemm(
    const unsigned short* __restrict__ A2, const unsigned short* __restrict__ W2,
    const float* __restrict__ bias, const float* __restrict__ a_src,
    const float* __restrict__ a_trg, unsigned short* __restrict__ projb,
    float* __restrict__ ssrc, float* __restrict__ strg,
    float* __restrict__ out, int M)
{
    __shared__ __align__(16) unsigned short sAh[8192], sAl[8192], sBh[8192], sBl[8192];

    const int tid = threadIdx.x;
    const int l   = tid & 63;
    const int w   = tid >> 6;       // wave 0..3
    const int wr  = w >> 1, wc = w & 1;
    const int brow = blockIdx.x * 128;
    const int bcol = blockIdx.y * 128;

    f32x4 acc[4][4];
    #pragma unroll
    for (int a = 0; a < 4; ++a)
        #pragma unroll
        for (int b = 0; b < 4; ++b) acc[a][b] = (f32x4){0.f, 0.f, 0.f, 0.f};

    const int srow = l >> 3;              // row within 8-row group
    const int sseg = (l & 7) ^ srow;      // inverse-swizzled source 16B-segment

    for (int kk = 0; kk < 4; ++kk) {
        #pragma unroll
        for (int i = 0; i < 4; ++i) {
            const int rl  = w * 32 + i * 8 + srow;     // local row 0..127
            const int lds = (w * 32 + i * 8) * 64;     // ushort index (row start)
            int ga = brow + rl; if (ga >= M) ga = M - 1;
            const unsigned short* gA = A2 + (size_t)ga * 512 + kk * 64 + sseg * 8;
            const unsigned short* gB = W2 + (size_t)(bcol + rl) * 512 + kk * 64 + sseg * 8;
            gload16(gA,       &sAh[lds]);
            gload16(gA + 256, &sAl[lds]);
            gload16(gB,       &sBh[lds]);
            gload16(gB + 256, &sBl[lds]);
        }
        __syncthreads();

        #pragma unroll
        for (int ks = 0; ks < 2; ++ks) {
            const int sg = ((ks * 4) + (l >> 4)) ^ (l & 7);   // swizzled read segment
            bf16x8 ah[4], al[4], bh[4], bl[4];
            #pragma unroll
            for (int f = 0; f < 4; ++f) {
                const int ra = wr * 64 + f * 16 + (l & 15);
                const int rb = wc * 64 + f * 16 + (l & 15);
                ah[f] = *(const bf16x8*)&sAh[ra * 64 + sg * 8];
                al[f] = *(const bf16x8*)&sAl[ra * 64 + sg * 8];
                bh[f] = *(const bf16x8*)&sBh[rb * 64 + sg * 8];
                bl[f] = *(const bf16x8*)&sBl[rb * 64 + sg * 8];
            }
            #pragma unroll
            for (int fm = 0; fm < 4; ++fm)
                #pragma unroll
                for (int fn = 0; fn < 4; ++fn) {
                    acc[fm][fn] = __builtin_amdgcn_mfma_f32_16x16x32_bf16(ah[fm], bh[fn], acc[fm][fn], 0, 0, 0);
                    acc[fm][fn] = __builtin_amdgcn_mfma_f32_16x16x32_bf16(ah[fm], bl[fn], acc[fm][fn], 0, 0, 0);
                    acc[fm][fn] = __builtin_amdgcn_mfma_f32_16x16x32_bf16(al[fm], bh[fn], acc[fm][fn], 0, 0, 0);
                }
        }
        __syncthreads();
    }

    // epilogue: C/D layout col=lane&15, row=(lane>>4)*4+q
    if (bcol < 256) {
        float as[4], at[4];
        #pragma unroll
        for (int fn = 0; fn < 4; ++fn) {
            const int col = bcol + wc * 64 + fn * 16 + (l & 15);
            as[fn] = a_src[col];
            at[fn] = a_trg[col];
        }
        #pragma unroll
        for (int fn = 0; fn < 4; ++fn) {
            const int col = bcol + wc * 64 + fn * 16 + (l & 15);
            #pragma unroll
            for (int fm = 0; fm < 4; ++fm) {
                const int r0 = brow + wr * 64 + fm * 16 + (l >> 4) * 4;
                #pragma unroll
                for (int q = 0; q < 4; ++q) {
                    const int row = r0 + q;
                    if (row < M) projb[(size_t)row * 256 + col] = f2bf(acc[fm][fn][q]);
                }
            }
        }
        const int headA = ((bcol + wc * 64) >> 5);
        const int headB = headA + 1;
        #pragma unroll
        for (int fm = 0; fm < 4; ++fm) {
            #pragma unroll
            for (int q = 0; q < 4; ++q) {
                float p0 = acc[fm][0][q] * as[0] + acc[fm][1][q] * as[1];
                float p1 = acc[fm][2][q] * as[2] + acc[fm][3][q] * as[3];
                float t0 = acc[fm][0][q] * at[0] + acc[fm][1][q] * at[1];
                float t1 = acc[fm][2][q] * at[2] + acc[fm][3][q] * at[3];
                #pragma unroll
                for (int m = 1; m < 16; m <<= 1) {
                    p0 += __shfl_xor(p0, m, 64);
                    p1 += __shfl_xor(p1, m, 64);
                    t0 += __shfl_xor(t0, m, 64);
                    t1 += __shfl_xor(t1, m, 64);
                }
                if ((l & 15) == 0) {
                    const int row = brow + wr * 64 + fm * 16 + (l >> 4) * 4 + q;
                    if (row < M) {
                        ssrc[(size_t)row * NH + headA] = p0;
                        ssrc[(size_t)row * NH + headB] = p1;
                        strg[(size_t)row * NH + headA] = t0;
                        strg[(size_t)row * NH + headB] = t1;
                    }
                }
            }
        }
    } else {
        #pragma unroll
        for (int fn = 0; fn < 4; ++fn) {
            const int col = bcol + wc * 64 + fn * 16 + (l & 15);
            const float bv = bias[col - 256];
            float* dst = out + (col - 256);
            #pragma unroll
            for (int fm = 0; fm < 4; ++fm) {
                const int r0 = brow + wr * 64 + fm * 16 + (l >> 4) * 4;
                #pragma unroll
                for (int q = 0; q < 4; ++q) {
                    const int row = r0 + q;
                    if (row < M) dst[(size_t)row * 256] = acc[fm][fn][q] + bv;
                }
            }
        }
    }
}

__device__ __forceinline__ float lrelu(float v) { return v > 0.f ? v : 0.2f * v; }

// ---------------- exclusive prefix scan of deg -> rp (multi-block, proven) ----------------
__global__ __launch_bounds__(256) void scan1_k(
    const int* __restrict__ deg, int* __restrict__ rp, int* __restrict__ bsum, int N)
{
    __shared__ int sh[256];
    const int tid = threadIdx.x;
    const int base = blockIdx.x * 4096 + tid * 16;
    int v[16], pre[16];
    int s = 0;
    #pragma unroll
    for (int i = 0; i < 16; ++i) {
        int idx = base + i;
        v[i] = (idx < N) ? deg[idx] : 0;
        pre[i] = s; s += v[i];
    }
    sh[tid] = s;
    __syncthreads();
    #pragma unroll
    for (int off = 1; off < 256; off <<= 1) {
        int t = (tid >= off) ? sh[tid - off] : 0;
        __syncthreads();
        sh[tid] += t;
        __syncthreads();
    }
    int texcl = sh[tid] - s;
    #pragma unroll
    for (int i = 0; i < 16; ++i) {
        int idx = base + i;
        if (idx < N) rp[idx] = texcl + pre[i];
    }
    if (tid == 255) bsum[blockIdx.x] = sh[255];
}

__global__ void scan2_k(int* bsum, int nsb) {
    if (threadIdx.x == 0 && blockIdx.x == 0) {
        int s = 0;
        for (int b = 0; b < nsb; ++b) { int v = bsum[b]; bsum[b] = s; s += v; }
    }
}

__global__ __launch_bounds__(256) void scan3_k(
    int* __restrict__ rp, const int* __restrict__ bsum,
    int* __restrict__ cursor, int N, int E)
{
    int gid = blockIdx.x * 256 + threadIdx.x;
    if (gid < N) {
        int v = rp[gid] + bsum[gid >> 12];
        rp[gid] = v;
        cursor[gid] = v;
    }
    if (gid == 0) rp[N] = E;
}

// ---------------- scatter: bucket src ids by target ----------------
__global__ __launch_bounds__(256) void scatter_k(
    const int* __restrict__ ei, int* __restrict__ cursor,
    int* __restrict__ col, int E)
{
    int gid = blockIdx.x * 256 + threadIdx.x;
    int stride = gridDim.x * 256;
    for (int e = gid; e < E; e += stride) {
        int s = ei[e];
        int t = ei[(size_t)E + e];
        int pos = atomicAdd(&cursor[t], 1);
        col[pos] = s;
    }
}

// ---------------- gather + finalize: one wave per node, 8 edges in flight ----------------
// Half-wave (32 lanes) owns 4 edges per iter: lane covers 8 bf16 cols (16B), head = hl>>2.
__global__ __launch_bounds__(256) void gather_k(
    const int* __restrict__ rp, const int* __restrict__ col,
    const float* __restrict__ ssrc, const float* __restrict__ strg,
    const unsigned short* __restrict__ projb, float* __restrict__ out, int N)
{
    const int lane = threadIdx.x & 63;
    const int node = blockIdx.x * 4 + (threadIdx.x >> 6);
    if (node >= N) return;
    const int half = lane >> 5;
    const int hl   = lane & 31;
    const int h    = hl >> 2;

    const float st = strg[(size_t)node * NH + h];
    const int beg = rp[node], end = rp[node + 1];

    float a0 = 0.f, a1 = 0.f, a2 = 0.f, a3 = 0.f,
          a4 = 0.f, a5 = 0.f, a6 = 0.f, a7 = 0.f, den = 0.f;

    for (int i0 = beg; i0 < end; i0 += 64) {
        int ci = (i0 + lane < end) ? col[i0 + lane] : 0;
        int cnt = end - i0; if (cnt > 64) cnt = 64;
        for (int k = 0; k < cnt; k += 8) {
            const int eb = k + half * 4;
            const int e0 = eb, e1 = eb + 1, e2 = eb + 2, e3 = eb + 3;
            int s0 = __shfl(ci, e0 < 64 ? e0 : 63, 64);
            int s1 = __shfl(ci, e1 < 64 ? e1 : 63, 64);
            int s2 = __shfl(ci, e2 < 64 ? e2 : 63, 64);
            int s3 = __shfl(ci, e3 < 64 ? e3 : 63, 64);
            uint4 r0 = *(const uint4*)&projb[(size_t)s0 * HF + hl * 8];
            uint4 r1 = *(const uint4*)&projb[(size_t)s1 * HF + hl * 8];
            uint4 r2 = *(const uint4*)&projb[(size_t)s2 * HF + hl * 8];
            uint4 r3 = *(const uint4*)&projb[(size_t)s3 * HF + hl * 8];
            float es0 = (e0 < cnt) ? __expf(lrelu(ssrc[(size_t)s0 * NH + h] + st)) : 0.f;
            float es1 = (e1 < cnt) ? __expf(lrelu(ssrc[(size_t)s1 * NH + h] + st)) : 0.f;
            float es2 = (e2 < cnt) ? __expf(lrelu(ssrc[(size_t)s2 * NH + h] + st)) : 0.f;
            float es3 = (e3 < cnt) ? __expf(lrelu(ssrc[(size_t)s3 * NH + h] + st)) : 0.f;
            a0 += __uint_as_float(r0.x << 16) * es0 + __uint_as_float(r1.x << 16) * es1
                + __uint_as_float(r2.x << 16) * es2 + __uint_as_float(r3.x << 16) * es3;
            a1 += __uint_as_float(r0.x & 0xffff0000u) * es0 + __uint_as_float(r1.x & 0xffff0000u) * es1
                + __uint_as_float(r2.x & 0xffff0000u) * es2 + __uint_as_float(r3.x & 0xffff0000u) * es3;
            a2 += __uint_as_float(r0.y << 16) * es0 + __uint_as_float(r1.y << 16) * es1
                + __uint_as_float(r2.y << 16) * es2 + __uint_as_float(r3.y << 16) * es3;
            a3 += __uint_as_float(r0.y & 0xffff0000u) * es0 + __uint_as_float(r1.y & 0xffff0000u) * es1
                + __uint_as_float(r2.y & 0xffff0000u) * es2 + __uint_as_float(r3.y & 0xffff0000u) * es3;
            a4 += __uint_as_float(r0.z << 16) * es0 + __uint_as_float(r1.z << 16) * es1
                + __uint_as_float(r2.z << 16) * es2 + __uint_as_float(r3.z << 16) * es3;
            a5 += __uint_as_float(r0.z & 0xffff0000u) * es0 + __uint_as_float(r1.z & 0xffff0000u) * es1
                + __uint_as_float(r2.z & 0xffff0000u) * es2 + __uint_as_float(r3.z & 0xffff0000u) * es3;
            a6 += __uint_as_float(r0.w << 16) * es0 + __uint_as_float(r1.w << 16) * es1
                + __uint_as_float(r2.w << 16) * es2 + __uint_as_float(r3.w << 16) * es3;
            a7 += __uint_as_float(r0.w & 0xffff0000u) * es0 + __uint_as_float(r1.w & 0xffff0000u) * es1
                + __uint_as_float(r2.w & 0xffff0000u) * es2 + __uint_as_float(r3.w & 0xffff0000u) * es3;
            den += es0 + es1 + es2 + es3;
        }
    }

    // combine the two halves (lane i and i+32 hold same col-range)
    a0 += __shfl_xor(a0, 32, 64);  a1 += __shfl_xor(a1, 32, 64);
    a2 += __shfl_xor(a2, 32, 64);  a3 += __shfl_xor(a3, 32, 64);
    a4 += __shfl_xor(a4, 32, 64);  a5 += __shfl_xor(a5, 32, 64);
    a6 += __shfl_xor(a6, 32, 64);  a7 += __shfl_xor(a7, 32, 64);
    den += __shfl_xor(den, 32, 64);

    const float inv = 1.f / (den + 1e-16f);
    const size_t ob = (size_t)node * HF + hl * 8 + half * 4;
    float4 sk = *(const float4*)&out[ob];
    float c0, c1, c2, c3;
    if (half == 0) { c0 = a0; c1 = a1; c2 = a2; c3 = a3; }
    else           { c0 = a4; c1 = a5; c2 = a6; c3 = a7; }
    float4 v;
    v.x = c0 * inv + sk.x;
    v.y = c1 * inv + sk.y;
    v.z = c2 * inv + sk.z;
    v.w = c3 * inv + sk.w;
    v.x = v.x > 0.f ? v.x : expm1f(v.x);
    v.y = v.y > 0.f ? v.y : expm1f(v.y);
    v.z = v.z > 0.f ? v.z : expm1f(v.z);
    v.w = v.w > 0.f ? v.w : expm1f(v.w);
    *(float4*)&out[ob] = v;
}

extern "C" void kernel_launch(void* const* d_in, const int* in_sizes, int n_in,
                              void* d_out, int out_size, void* d_ws, size_t ws_size,
                              hipStream_t stream) {
    const float* x     = (const float*)d_in[0];
    const int*   ei    = (const int*)d_in[1];
    const float* Wp    = (const float*)d_in[2];
    const float* a_src = (const float*)d_in[3];
    const float* a_trg = (const float*)d_in[4];
    const float* Wskip = (const float*)d_in[5];
    const float* bias  = (const float*)d_in[6];
    float* out = (float*)d_out;

    const int N = in_sizes[0] / FIN;
    const int E = in_sizes[1] / 2;
    const int nsb = (N + 4095) / 4096;

    // workspace layout
    unsigned short* projb = (unsigned short*)d_ws;               // N*HF bf16
    float* ssrc          = (float*)(projb + (size_t)N * HF);     // N*NH
    float* strg          = ssrc + (size_t)N * NH;                // N*NH
    unsigned short* A2   = (unsigned short*)(strg + (size_t)N * NH);  // N*512
    unsigned short* W2   = A2 + (size_t)N * 512;                 // 512*512
    int* deg             = (int*)(W2 + 512 * 512);               // N
    int* rp              = deg + N;                              // N+1
    int* cursor          = rp + (N + 1);                         // N
    int* bsum            = cursor + N;                           // 16
    int* col             = bsum + 16;                            // E

    hipMemsetAsync(deg, 0, (size_t)N * sizeof(int), stream);

    const int convBlocks = (N + 512 + 3) / 4;
    convert_hist_k<<<convBlocks + 1024, 256, 0, stream>>>(
        x, Wp, Wskip, A2, W2, ei, deg, N, E, convBlocks);

    dim3 ggrid((N + 127) / 128, 4);
    mfma_gemm<<<ggrid, 256, 0, stream>>>(A2, W2, bias, a_src, a_trg,
                                         projb, ssrc, strg, out, N);

    scan1_k<<<nsb, 256, 0, stream>>>(deg, rp, bsum, N);
    scan2_k<<<1, 64, 0, stream>>>(bsum, nsb);
    scan3_k<<<(N + 255) / 256, 256, 0, stream>>>(rp, bsum, cursor, N, E);

    scatter_k<<<1024, 256, 0, stream>>>(ei, cursor, col, E);

    gather_k<<<(N + 3) / 4, 256, 0, stream>>>(rp, col, ssrc, strg, projb, out, N);
}